// Round 7
// baseline (199.551 us; speedup 1.0000x reference)
//
#include <hip/hip_runtime.h>
#include <hip/hip_bf16.h>
#include <stdint.h>

// Problem dims
#define T_HRZ 1024
#define NBAT  128
#define NHID  256
#define NPAIR 128
#define NUIN  64
#define NYOUT 64
#define LCH   16   // chunk length
#define CCH   64   // number of chunks
#define GCH   4    // chunks per group (per block)
#define NGRP  16   // groups per batch chain = CCH/GCH

// Workspace layout (float offsets). ~2.3 MB total.
#define WS_LAM   0         // lr[128], li[128]
#define WS_LAML  256       // lambda^16 r[128], i[128]
#define WS_X0P   512       // x0 pair-interleaved [b][j][2] : 128*128*2
#define WS_WBU   33280     // bf16 B-frags for Bu GEMM [nt16][kk2][lane64][j8]
#define WS_WBY   41472     // bf16 B-frags for Y GEMM  [nt4][kk8][lane64][j8]
#define WS_SPUB  49664     // u64 group-sum publications [g][b][j] (524288 floats)
#define WS_CNT   573952    // u32 mask[b] at b*16 (stride 64B) + ticket at [2048]

// X16 LDS tile: packed bf16 pairs, pitch 264 shorts (132 dwords, 132%32=4)
#define X16_PITCH 264
// XA LDS tile: padded A-frag layout, b-stride 136 shorts, kk-stride 552
#define XA_SB 136
#define XA_SK 552

typedef __attribute__((ext_vector_type(8))) short short8;
typedef __attribute__((ext_vector_type(4))) float float4v;

union Frag { short8 s8; unsigned int u32[4]; };

__device__ __forceinline__ unsigned int f2bf_bits(float x) {
  unsigned int u = __float_as_uint(x);
  return (u + 0x7fffu + ((u >> 16) & 1u)) >> 16;  // RNE
}

__device__ __forceinline__ unsigned int pkbf(float a, float b) {
  __hip_bfloat162 h = __float22bfloat162_rn(make_float2(a, b));
  union { __hip_bfloat162 h2; unsigned int u; } cv; cv.h2 = h; return cv.u;
}

// ---------------------------------------------------------------------------
// K1: prep. grid (NBAT+3) x 256. Also zeroes join masks + ticket each launch.
// ---------------------------------------------------------------------------
__global__ __launch_bounds__(256) void k_prep(
    const float* __restrict__ y0, const float* __restrict__ lrc,
    const float* __restrict__ lic, const float* __restrict__ Bm,
    const float* __restrict__ Wy2x, const float* __restrict__ by2x,
    const float* __restrict__ Wx2y, float* __restrict__ ws)
{
  int blk = blockIdx.x;
  int h = threadIdx.x;  // 0..255
  if (blk < NBAT) {
    __shared__ float y0s[NYOUT];
    if (h < NYOUT) y0s[h] = y0[blk * NYOUT + h];
    __syncthreads();
    float acc = by2x[h];
    const float* wr = Wy2x + h * NYOUT;
#pragma unroll 16
    for (int k = 0; k < NYOUT; ++k) acc += y0s[k] * wr[k];
    int j = h & (NPAIR - 1);
    int comp = h >> 7;
    ws[WS_X0P + (blk * NPAIR + j) * 2 + comp] = acc;
  } else if (blk == NBAT) {
    // zero join masks + ticket (must happen before k_main each launch)
    unsigned int* fl = (unsigned int*)(ws + WS_CNT);
    for (int i = h; i < NBAT * 16 + 1; i += 256) fl[i] = 0u;
    if (h < NPAIR) {
      float a  = fabsf(lrc[h]);
      float r  = expf(-a);
      float th = 1.5707963267948966f * lic[h];
      float lr = r * cosf(th);
      float li = r * sinf(th);
      ws[WS_LAM + h]         = lr;
      ws[WS_LAM + NPAIR + h] = li;
      float pr = lr, pi_ = li;
      for (int l = 1; l < LCH; ++l) {
        float nr = pr * lr - pi_ * li;
        float ni = pr * li + pi_ * lr;
        pr = nr; pi_ = ni;
      }
      ws[WS_LAML + h]         = pr;  // lambda^16
      ws[WS_LAML + NPAIR + h] = pi_;
    }
  } else if (blk == NBAT + 1) {
    unsigned short* wbu = (unsigned short*)(ws + WS_WBU);
    for (int idx = h; idx < 16384; idx += 256) {
      int nt   = idx >> 10;
      int kk   = (idx >> 9) & 1;
      int lane = (idx >> 3) & 63;
      int jj   = idx & 7;
      int u  = kk * 32 + (lane >> 4) * 8 + jj;
      int hh = nt * 16 + (lane & 15);
      float a2 = fabsf(lrc[hh & (NPAIR - 1)]);
      float nf = sqrtf(1.f - expf(-2.f * a2));
      wbu[idx] = (unsigned short)f2bf_bits(Bm[hh * NUIN + u] * nf);
    }
  } else {
    unsigned short* wby = (unsigned short*)(ws + WS_WBY);
    for (int idx = h; idx < 16384; idx += 256) {
      int nt   = idx >> 12;
      int kk   = (idx >> 9) & 7;
      int lane = (idx >> 3) & 63;
      int jj   = idx & 7;
      int hh = kk * 32 + (lane >> 4) * 8 + jj;
      int y  = nt * 16 + (lane & 15);
      wby[idx] = (unsigned short)f2bf_bits(Wx2y[y * NHID + hh]);
    }
  }
}

// ---------------------------------------------------------------------------
// K2: fused single-pass scan with parallel lookback JOIN (no serial chain).
// grid NGRP*NBAT x 128 (2 waves). Ticket -> (g,b); block owns GCH=4 chunks.
//
// __launch_bounds__(128, 4): 2048 blocks = EXACTLY 8 blocks/CU -> the whole
// grid is co-resident in ONE generation (round-5's (128,3) left 512 blocks
// for a second generation, doubling the latency chain: 86us at 24% occ).
// To fit the 128-VGPR cap without round-3's wholesale pk spill, pass-1 MFMA
// accumulators are split into two halves of acc[4] (16 VGPRs peak instead
// of 32 alongside the growing pk[]), and Lam^64 derivation moved after
// pass 1. Peak live ~= pk48 + acc16 + afr8 + ~25 misc < 128.
// ---------------------------------------------------------------------------
__global__ __launch_bounds__(128, 4) void k_main(
    const float* __restrict__ U, const float* __restrict__ bx2y,
    float* __restrict__ out, float* __restrict__ ws)
{
  // X16 (16*264=4224 shorts) and XA (8*552=4416 shorts) alias SM; every
  // X16 read precedes every XA write across a barrier and vice versa.
  __shared__ unsigned short SM[8 * XA_SK];
  __shared__ unsigned int vid_s;
  int tid = threadIdx.x, wave = tid >> 6, lane = tid & 63;
  int l15 = lane & 15, q = lane >> 4;

  unsigned int* cnt = (unsigned int*)(ws + WS_CNT);
  if (tid == 0) vid_s = atomicAdd(cnt + NBAT * 16, 1u);  // ticket = start order
  __syncthreads();
  unsigned int vid = vid_s;
  int g = (int)(vid >> 7);        // group, 0..15
  int b = (int)(vid & (NBAT - 1));

  int j = tid;
  float lr = ws[WS_LAM + j],  li = ws[WS_LAM + NPAIR + j];

  const short8* wbu = (const short8*)(ws + WS_WBU);
  float4v z = {0.f, 0.f, 0.f, 0.f};

  unsigned int pk[GCH][LCH];   // 64 VGPRs: packed bf16 Bu, kept for pass 2
  float S1 = 0.f, S2 = 0.f;    // running group sum (64-step register scan)

  // ---- pass 1: per-chunk Bu MFMA + transpose; accumulate S ----
#pragma unroll
  for (int k = 0; k < GCH; ++k) {
    int c = g * GCH + k;
    const float* urow = U + ((size_t)(c * LCH + l15) * NBAT + b) * NUIN;
    Frag afr[2];
#pragma unroll
    for (int kk = 0; kk < 2; ++kk) {
      int u0 = kk * 32 + q * 8;
      float4 va = *(const float4*)(urow + u0);
      float4 vb = *(const float4*)(urow + u0 + 4);
      afr[kk].u32[0] = pkbf(va.x, va.y);
      afr[kk].u32[1] = pkbf(va.z, va.w);
      afr[kk].u32[2] = pkbf(vb.x, vb.y);
      afr[kk].u32[3] = pkbf(vb.z, vb.w);
    }
    // Two halves of 4 accumulators: halves peak VGPR pressure vs acc[8];
    // each half's results are retired to LDS before the next half issues.
#pragma unroll
    for (int half = 0; half < 2; ++half) {
      float4v acc[4];
#pragma unroll
      for (int n = 0; n < 4; ++n) acc[n] = z;
#pragma unroll
      for (int n = 0; n < 4; ++n) {
        int nt = wave * 8 + half * 4 + n;
        acc[n] = __builtin_amdgcn_mfma_f32_16x16x32_bf16(afr[0].s8, wbu[(nt * 2 + 0) * 64 + lane], acc[n], 0, 0, 0);
        acc[n] = __builtin_amdgcn_mfma_f32_16x16x32_bf16(afr[1].s8, wbu[(nt * 2 + 1) * 64 + lane], acc[n], 0, 0, 0);
      }
      // C-layout (t=q*4+r, h=nt*16+l15) -> packed pair LDS
#pragma unroll
      for (int n = 0; n < 4; ++n) {
        int hh = (wave * 8 + half * 4 + n) * 16 + l15;
        int off = (hh & 127) * 2 + (hh >> 7);
#pragma unroll
        for (int r = 0; r < 4; ++r)
          SM[(q * 4 + r) * X16_PITCH + off] = (unsigned short)f2bf_bits(acc[n][r]);
      }
    }
    __syncthreads();
#pragma unroll
    for (int l = 0; l < LCH; ++l)
      pk[k][l] = *(const unsigned int*)(SM + l * X16_PITCH + j * 2);
#pragma unroll
    for (int l = 0; l < LCH; ++l) {
      float v1 = __uint_as_float(pk[k][l] << 16);
      float v2 = __uint_as_float(pk[k][l] & 0xffff0000u);
      float n1 = lr * S1 - li * S2 + v1;
      float n2 = li * S1 + lr * S2 + v2;
      S1 = n1; S2 = n2;
    }
    __syncthreads();  // pk reads done before next chunk overwrites X16
  }

  // ---- publish S (independent of predecessors => no serial chain) ----
  unsigned long long* spub = (unsigned long long*)(ws + WS_SPUB);
  const size_t cs = (size_t)NBAT * NPAIR;
  size_t o0 = (size_t)b * NPAIR + j;
  if (g < NGRP - 1) {
    unsigned long long pv = ((unsigned long long)__float_as_uint(S2) << 32)
                          |  (unsigned long long)__float_as_uint(S1);
    __hip_atomic_store(spub + (size_t)g * cs + o0, pv,
                       __ATOMIC_RELAXED, __HIP_MEMORY_SCOPE_AGENT);
  }
  // Barrier waits each thread's vmcnt(0): all S atomics are at the coherence
  // point before tid0 flips the mask bit. No wbl2/inv needed (all atomics).
  __syncthreads();
  if (tid == 0 && g < NGRP - 1)
    atomicOr(cnt + b * 16, 1u << g);

  // Lam^64 derived here (not at top) to keep pass-1 register pressure down.
  float L16r = ws[WS_LAML + j], L16i = ws[WS_LAML + NPAIR + j];
  float L32r = L16r * L16r - L16i * L16i, L32i = 2.f * L16r * L16i;
  float L64r = L32r * L32r - L32i * L32i, L64i = 2.f * L32r * L32i;

  // ---- join: wait for ALL predecessors' S bits, then local Horner ----
  float e1, e2;
  e1 = ws[WS_X0P + (b * NPAIR + j) * 2 + 0];
  e2 = ws[WS_X0P + (b * NPAIR + j) * 2 + 1];
  if (g > 0) {
    unsigned int need = (1u << g) - 1u;
    if (tid == 0) {
      while ((__hip_atomic_load(cnt + b * 16, __ATOMIC_RELAXED,
                                __HIP_MEMORY_SCOPE_AGENT) & need) != need)
        __builtin_amdgcn_s_sleep(1);
    }
    __syncthreads();
    unsigned long long sv[NGRP - 1];
#pragma unroll
    for (int g2 = 0; g2 < NGRP - 1; ++g2)
      if (g2 < g)
        sv[g2] = __hip_atomic_load(spub + (size_t)g2 * cs + o0,
                                   __ATOMIC_RELAXED, __HIP_MEMORY_SCOPE_AGENT);
#pragma unroll
    for (int g2 = 0; g2 < NGRP - 1; ++g2)
      if (g2 < g) {
        float s1 = __uint_as_float((unsigned int)sv[g2]);
        float s2 = __uint_as_float((unsigned int)(sv[g2] >> 32));
        float n1 = L64r * e1 - L64i * e2 + s1;
        float n2 = L64i * e1 + L64r * e2 + s2;
        e1 = n1; e2 = n2;
      }
  }

  // ---- pass 2: finish scan from e; per chunk write XA, Y-MFMA, store ----
  const short8* wby = (const short8*)(ws + WS_WBY);
  int base1 = (j >> 5) * XA_SK       + ((j >> 3) & 3) * XA_SB + (j & 7);
  int base2 = ((j >> 5) + 4) * XA_SK + ((j >> 3) & 3) * XA_SB + (j & 7);
  float x1 = e1, x2 = e2;
  float bias0 = bx2y[(wave * 2 + 0) * 16 + l15];
  float bias1 = bx2y[(wave * 2 + 1) * 16 + l15];
#pragma unroll
  for (int k = 0; k < GCH; ++k) {
    int c = g * GCH + k;
#pragma unroll
    for (int l = 0; l < LCH; ++l) {
      float v1 = __uint_as_float(pk[k][l] << 16);
      float v2 = __uint_as_float(pk[k][l] & 0xffff0000u);
      float n1 = lr * x1 - li * x2 + v1;
      float n2 = li * x1 + lr * x2 + v2;
      x1 = n1; x2 = n2;
      SM[base1 + l * 8] = (unsigned short)f2bf_bits(x1);
      SM[base2 + l * 8] = (unsigned short)f2bf_bits(x2);
    }
    __syncthreads();
    float4v acc0 = z, acc1 = z;
    int nt0 = wave * 2, nt1 = nt0 + 1;
#pragma unroll
    for (int kk = 0; kk < 8; ++kk) {
      short8 a = *(const short8*)(SM + kk * XA_SK + q * XA_SB + l15 * 8);
      acc0 = __builtin_amdgcn_mfma_f32_16x16x32_bf16(a, wby[(nt0 * 8 + kk) * 64 + lane], acc0, 0, 0, 0);
      acc1 = __builtin_amdgcn_mfma_f32_16x16x32_bf16(a, wby[(nt1 * 8 + kk) * 64 + lane], acc1, 0, 0, 0);
    }
#pragma unroll
    for (int r = 0; r < 4; ++r) {
      int row = q * 4 + r;  // t within chunk
      size_t o = ((size_t)(c * LCH + row) * NBAT + b) * NYOUT;
      out[o + nt0 * 16 + l15] = acc0[r] + bias0;
      out[o + nt1 * 16 + l15] = acc1[r] + bias1;
    }
    if (k < GCH - 1) __syncthreads();  // XA reads done before next overwrite
  }
}

// ---------------------------------------------------------------------------
extern "C" void kernel_launch(void* const* d_in, const int* in_sizes, int n_in,
                              void* d_out, int out_size, void* d_ws, size_t ws_size,
                              hipStream_t stream) {
  (void)in_sizes; (void)n_in; (void)out_size; (void)ws_size;
  const float* y0   = (const float*)d_in[0];
  const float* U    = (const float*)d_in[1];
  const float* lrc  = (const float*)d_in[2];
  const float* lic  = (const float*)d_in[3];
  const float* Bm   = (const float*)d_in[4];
  const float* Wy2x = (const float*)d_in[5];
  const float* by2x = (const float*)d_in[6];
  const float* Wx2y = (const float*)d_in[7];
  const float* bx2y = (const float*)d_in[8];
  float* out = (float*)d_out;
  float* ws  = (float*)d_ws;

  k_prep<<<dim3(NBAT + 3), 256, 0, stream>>>(y0, lrc, lic, Bm, Wy2x, by2x, Wx2y, ws);
  k_main<<<dim3(NGRP * NBAT), 128, 0, stream>>>(U, bx2y, out, ws);
}

// Round 9
// 175.235 us; speedup vs baseline: 1.1388x; 1.1388x over previous
//
#include <hip/hip_runtime.h>
#include <hip/hip_bf16.h>
#include <stdint.h>

// Problem dims
#define T_HRZ 1024
#define NBAT  128
#define NHID  256
#define NPAIR 128
#define NUIN  64
#define NYOUT 64
#define LCH   16   // chunk length
#define CCH   64   // number of chunks
#define GCH   4    // chunks per group (per block)
#define NGRP  16   // groups per batch chain = CCH/GCH

// Workspace layout (float offsets). ~2.3 MB total.
#define WS_LAM   0         // lr[128], li[128]
#define WS_LAML  256       // lambda^16 r[128], i[128]
#define WS_X0P   512       // x0 pair-interleaved [b][j][2] : 128*128*2
#define WS_WBU   33280     // bf16 B-frags for Bu GEMM [nt16][kk2][lane64][j8]
#define WS_WBY   41472     // bf16 B-frags for Y GEMM  [nt4][kk8][lane64][j8]
#define WS_SPUB  49664     // u64 group-sum publications [g][b][j] (524288 floats)
#define WS_CNT   573952    // u32 mask[b] at b*16 (stride 64B) + ticket at [2048]

// X16 LDS tile: packed bf16 pairs, pitch 264 shorts (132 dwords, 132%32=4)
#define X16_PITCH 264
// XA LDS tile: padded A-frag layout, b-stride 136 shorts, kk-stride 552
#define XA_SB 136
#define XA_SK 552

typedef __attribute__((ext_vector_type(8))) short short8;
typedef __attribute__((ext_vector_type(4))) float float4v;

union Frag { short8 s8; unsigned int u32[4]; };

__device__ __forceinline__ unsigned int f2bf_bits(float x) {
  unsigned int u = __float_as_uint(x);
  return (u + 0x7fffu + ((u >> 16) & 1u)) >> 16;  // RNE
}

__device__ __forceinline__ unsigned int pkbf(float a, float b) {
  __hip_bfloat162 h = __float22bfloat162_rn(make_float2(a, b));
  union { __hip_bfloat162 h2; unsigned int u; } cv; cv.h2 = h; return cv.u;
}

// ---------------------------------------------------------------------------
// K1: prep. grid (NBAT+3) x 256. Also zeroes join masks + ticket each launch.
// ---------------------------------------------------------------------------
__global__ __launch_bounds__(256) void k_prep(
    const float* __restrict__ y0, const float* __restrict__ lrc,
    const float* __restrict__ lic, const float* __restrict__ Bm,
    const float* __restrict__ Wy2x, const float* __restrict__ by2x,
    const float* __restrict__ Wx2y, float* __restrict__ ws)
{
  int blk = blockIdx.x;
  int h = threadIdx.x;  // 0..255
  if (blk < NBAT) {
    __shared__ float y0s[NYOUT];
    if (h < NYOUT) y0s[h] = y0[blk * NYOUT + h];
    __syncthreads();
    float acc = by2x[h];
    const float* wr = Wy2x + h * NYOUT;
#pragma unroll 16
    for (int k = 0; k < NYOUT; ++k) acc += y0s[k] * wr[k];
    int j = h & (NPAIR - 1);
    int comp = h >> 7;
    ws[WS_X0P + (blk * NPAIR + j) * 2 + comp] = acc;
  } else if (blk == NBAT) {
    // zero join masks + ticket (must happen before k_main each launch)
    unsigned int* fl = (unsigned int*)(ws + WS_CNT);
    for (int i = h; i < NBAT * 16 + 1; i += 256) fl[i] = 0u;
    if (h < NPAIR) {
      float a  = fabsf(lrc[h]);
      float r  = expf(-a);
      float th = 1.5707963267948966f * lic[h];
      float lr = r * cosf(th);
      float li = r * sinf(th);
      ws[WS_LAM + h]         = lr;
      ws[WS_LAM + NPAIR + h] = li;
      float pr = lr, pi_ = li;
      for (int l = 1; l < LCH; ++l) {
        float nr = pr * lr - pi_ * li;
        float ni = pr * li + pi_ * lr;
        pr = nr; pi_ = ni;
      }
      ws[WS_LAML + h]         = pr;  // lambda^16
      ws[WS_LAML + NPAIR + h] = pi_;
    }
  } else if (blk == NBAT + 1) {
    unsigned short* wbu = (unsigned short*)(ws + WS_WBU);
    for (int idx = h; idx < 16384; idx += 256) {
      int nt   = idx >> 10;
      int kk   = (idx >> 9) & 1;
      int lane = (idx >> 3) & 63;
      int jj   = idx & 7;
      int u  = kk * 32 + (lane >> 4) * 8 + jj;
      int hh = nt * 16 + (lane & 15);
      float a2 = fabsf(lrc[hh & (NPAIR - 1)]);
      float nf = sqrtf(1.f - expf(-2.f * a2));
      wbu[idx] = (unsigned short)f2bf_bits(Bm[hh * NUIN + u] * nf);
    }
  } else {
    unsigned short* wby = (unsigned short*)(ws + WS_WBY);
    for (int idx = h; idx < 16384; idx += 256) {
      int nt   = idx >> 12;
      int kk   = (idx >> 9) & 7;
      int lane = (idx >> 3) & 63;
      int jj   = idx & 7;
      int hh = kk * 32 + (lane >> 4) * 8 + jj;
      int y  = nt * 16 + (lane & 15);
      wby[idx] = (unsigned short)f2bf_bits(Wx2y[y * NHID + hh]);
    }
  }
}

// ---------------------------------------------------------------------------
// K2: fused single-pass scan, parallel-lookback join, Bu RECOMPUTE in pass 2.
// grid NGRP*NBAT x 128 (2 waves). Ticket -> (g,b); block owns GCH=4 chunks.
//
// Round-7 lesson: keeping pk[4][16] (64 VGPRs/thread) across pass1->pass2
// is physically incompatible with 8 blocks/CU (256 KB of VGPR file) -> the
// allocator spills it wholesale (VGPR=64, 64 MB scratch, 104 us). Fix:
// DON'T keep Bu. Pass 1 computes only the running sum S; pass 2 re-reads U
// and re-runs the Bu MFMA (bit-identical values). Costs ~33.5 MB extra U
// fetch + 3%-util MFMA; eliminates all scratch traffic and the reg cliff.
//
// X16 and XA are now SEPARATE LDS arrays (17.3 KB/block; 8 x 17.3 = 139 KB
// < 160 KB/CU) so pass 2 streams X16-read -> scan -> XA-write with no
// aliasing hazard, 2 barriers per chunk.
//
// __launch_bounds__(128, 4): 2048 blocks = exactly 8 blocks/CU, whole grid
// co-resident in one generation. Peak live regs ~ acc32+afr8+~30 < 128.
// ---------------------------------------------------------------------------
__global__ __launch_bounds__(128, 4) void k_main(
    const float* __restrict__ U, const float* __restrict__ bx2y,
    float* __restrict__ out, float* __restrict__ ws)
{
  __shared__ unsigned short X16s[LCH * X16_PITCH];  // 8448 B
  __shared__ unsigned short XAs[8 * XA_SK];         // 8832 B
  __shared__ unsigned int vid_s;
  int tid = threadIdx.x, wave = tid >> 6, lane = tid & 63;
  int l15 = lane & 15, q = lane >> 4;

  unsigned int* cnt = (unsigned int*)(ws + WS_CNT);
  if (tid == 0) vid_s = atomicAdd(cnt + NBAT * 16, 1u);  // ticket = start order
  __syncthreads();
  unsigned int vid = vid_s;
  int g = (int)(vid >> 7);        // group, 0..15
  int b = (int)(vid & (NBAT - 1));

  int j = tid;
  float lr = ws[WS_LAM + j],  li = ws[WS_LAM + NPAIR + j];

  const short8* wbu = (const short8*)(ws + WS_WBU);
  float4v z = {0.f, 0.f, 0.f, 0.f};

  float S1 = 0.f, S2 = 0.f;    // running group sum (64-step register scan)

  // ---- pass 1: per-chunk Bu MFMA + transpose; accumulate S only ----
#pragma unroll
  for (int k = 0; k < GCH; ++k) {
    int c = g * GCH + k;
    const float* urow = U + ((size_t)(c * LCH + l15) * NBAT + b) * NUIN;
    Frag afr[2];
#pragma unroll
    for (int kk = 0; kk < 2; ++kk) {
      int u0 = kk * 32 + q * 8;
      float4 va = *(const float4*)(urow + u0);
      float4 vb = *(const float4*)(urow + u0 + 4);
      afr[kk].u32[0] = pkbf(va.x, va.y);
      afr[kk].u32[1] = pkbf(va.z, va.w);
      afr[kk].u32[2] = pkbf(vb.x, vb.y);
      afr[kk].u32[3] = pkbf(vb.z, vb.w);
    }
    float4v acc[8];
#pragma unroll
    for (int n = 0; n < 8; ++n) acc[n] = z;
#pragma unroll
    for (int n = 0; n < 8; ++n) {
      int nt = wave * 8 + n;
      acc[n] = __builtin_amdgcn_mfma_f32_16x16x32_bf16(afr[0].s8, wbu[(nt * 2 + 0) * 64 + lane], acc[n], 0, 0, 0);
      acc[n] = __builtin_amdgcn_mfma_f32_16x16x32_bf16(afr[1].s8, wbu[(nt * 2 + 1) * 64 + lane], acc[n], 0, 0, 0);
    }
    // C-layout (t=q*4+r, h=(wave*8+n)*16+l15) -> packed pair LDS
#pragma unroll
    for (int n = 0; n < 8; ++n) {
      int hh = (wave * 8 + n) * 16 + l15;
      int off = (hh & 127) * 2 + (hh >> 7);
#pragma unroll
      for (int r = 0; r < 4; ++r)
        X16s[(q * 4 + r) * X16_PITCH + off] = (unsigned short)f2bf_bits(acc[n][r]);
    }
    __syncthreads();
#pragma unroll
    for (int l = 0; l < LCH; ++l) {
      unsigned int pkv = *(const unsigned int*)(X16s + l * X16_PITCH + j * 2);
      float v1 = __uint_as_float(pkv << 16);
      float v2 = __uint_as_float(pkv & 0xffff0000u);
      float n1 = lr * S1 - li * S2 + v1;
      float n2 = li * S1 + lr * S2 + v2;
      S1 = n1; S2 = n2;
    }
    __syncthreads();  // X16 reads done before next chunk overwrites it
  }

  // ---- publish S (independent of predecessors => no serial chain) ----
  unsigned long long* spub = (unsigned long long*)(ws + WS_SPUB);
  const size_t cs = (size_t)NBAT * NPAIR;
  size_t o0 = (size_t)b * NPAIR + j;
  if (g < NGRP - 1) {
    unsigned long long pv = ((unsigned long long)__float_as_uint(S2) << 32)
                          |  (unsigned long long)__float_as_uint(S1);
    __hip_atomic_store(spub + (size_t)g * cs + o0, pv,
                       __ATOMIC_RELAXED, __HIP_MEMORY_SCOPE_AGENT);
  }
  // Barrier waits each thread's vmcnt(0): all S atomics are at the coherence
  // point before tid0 flips the mask bit. No wbl2/inv needed (all atomics).
  __syncthreads();
  if (tid == 0 && g < NGRP - 1)
    atomicOr(cnt + b * 16, 1u << g);

  // Lam^64 derived here (not at top) to keep pass-1 register pressure down.
  float L16r = ws[WS_LAML + j], L16i = ws[WS_LAML + NPAIR + j];
  float L32r = L16r * L16r - L16i * L16i, L32i = 2.f * L16r * L16i;
  float L64r = L32r * L32r - L32i * L32i, L64i = 2.f * L32r * L32i;

  // ---- join: wait for ALL predecessors' S bits, then local Horner ----
  float e1, e2;
  e1 = ws[WS_X0P + (b * NPAIR + j) * 2 + 0];
  e2 = ws[WS_X0P + (b * NPAIR + j) * 2 + 1];
  if (g > 0) {
    unsigned int need = (1u << g) - 1u;
    if (tid == 0) {
      while ((__hip_atomic_load(cnt + b * 16, __ATOMIC_RELAXED,
                                __HIP_MEMORY_SCOPE_AGENT) & need) != need)
        __builtin_amdgcn_s_sleep(1);
    }
    __syncthreads();
    unsigned long long sv[NGRP - 1];
#pragma unroll
    for (int g2 = 0; g2 < NGRP - 1; ++g2)
      if (g2 < g)
        sv[g2] = __hip_atomic_load(spub + (size_t)g2 * cs + o0,
                                   __ATOMIC_RELAXED, __HIP_MEMORY_SCOPE_AGENT);
#pragma unroll
    for (int g2 = 0; g2 < NGRP - 1; ++g2)
      if (g2 < g) {
        float s1 = __uint_as_float((unsigned int)sv[g2]);
        float s2 = __uint_as_float((unsigned int)(sv[g2] >> 32));
        float n1 = L64r * e1 - L64i * e2 + s1;
        float n2 = L64i * e1 + L64r * e2 + s2;
        e1 = n1; e2 = n2;
      }
  }

  // ---- pass 2: RECOMPUTE Bu per chunk; scan from e -> XA -> Y-MFMA -> out --
  const short8* wby = (const short8*)(ws + WS_WBY);
  int base1 = (j >> 5) * XA_SK       + ((j >> 3) & 3) * XA_SB + (j & 7);
  int base2 = ((j >> 5) + 4) * XA_SK + ((j >> 3) & 3) * XA_SB + (j & 7);
  float x1 = e1, x2 = e2;
  float bias0 = bx2y[(wave * 2 + 0) * 16 + l15];
  float bias1 = bx2y[(wave * 2 + 1) * 16 + l15];
#pragma unroll
  for (int k = 0; k < GCH; ++k) {
    int c = g * GCH + k;
    // -- Bu recompute (bit-identical to pass 1) --
    const float* urow = U + ((size_t)(c * LCH + l15) * NBAT + b) * NUIN;
    Frag afr[2];
#pragma unroll
    for (int kk = 0; kk < 2; ++kk) {
      int u0 = kk * 32 + q * 8;
      float4 va = *(const float4*)(urow + u0);
      float4 vb = *(const float4*)(urow + u0 + 4);
      afr[kk].u32[0] = pkbf(va.x, va.y);
      afr[kk].u32[1] = pkbf(va.z, va.w);
      afr[kk].u32[2] = pkbf(vb.x, vb.y);
      afr[kk].u32[3] = pkbf(vb.z, vb.w);
    }
    float4v acc[8];
#pragma unroll
    for (int n = 0; n < 8; ++n) acc[n] = z;
#pragma unroll
    for (int n = 0; n < 8; ++n) {
      int nt = wave * 8 + n;
      acc[n] = __builtin_amdgcn_mfma_f32_16x16x32_bf16(afr[0].s8, wbu[(nt * 2 + 0) * 64 + lane], acc[n], 0, 0, 0);
      acc[n] = __builtin_amdgcn_mfma_f32_16x16x32_bf16(afr[1].s8, wbu[(nt * 2 + 1) * 64 + lane], acc[n], 0, 0, 0);
    }
#pragma unroll
    for (int n = 0; n < 8; ++n) {
      int hh = (wave * 8 + n) * 16 + l15;
      int off = (hh & 127) * 2 + (hh >> 7);
#pragma unroll
      for (int r = 0; r < 4; ++r)
        X16s[(q * 4 + r) * X16_PITCH + off] = (unsigned short)f2bf_bits(acc[n][r]);
    }
    __syncthreads();
    // -- scan from running x; stream X16 -> XA (separate arrays, no hazard) --
#pragma unroll
    for (int l = 0; l < LCH; ++l) {
      unsigned int pkv = *(const unsigned int*)(X16s + l * X16_PITCH + j * 2);
      float v1 = __uint_as_float(pkv << 16);
      float v2 = __uint_as_float(pkv & 0xffff0000u);
      float n1 = lr * x1 - li * x2 + v1;
      float n2 = li * x1 + lr * x2 + v2;
      x1 = n1; x2 = n2;
      XAs[base1 + l * 8] = (unsigned short)f2bf_bits(x1);
      XAs[base2 + l * 8] = (unsigned short)f2bf_bits(x2);
    }
    __syncthreads();
    // -- Y = X @ W_x2y^T via MFMA --
    float4v acc0 = z, acc1 = z;
    int nt0 = wave * 2, nt1 = nt0 + 1;
#pragma unroll
    for (int kk = 0; kk < 8; ++kk) {
      short8 a = *(const short8*)(XAs + kk * XA_SK + q * XA_SB + l15 * 8);
      acc0 = __builtin_amdgcn_mfma_f32_16x16x32_bf16(a, wby[(nt0 * 8 + kk) * 64 + lane], acc0, 0, 0, 0);
      acc1 = __builtin_amdgcn_mfma_f32_16x16x32_bf16(a, wby[(nt1 * 8 + kk) * 64 + lane], acc1, 0, 0, 0);
    }
#pragma unroll
    for (int r = 0; r < 4; ++r) {
      int row = q * 4 + r;  // t within chunk
      size_t o = ((size_t)(c * LCH + row) * NBAT + b) * NYOUT;
      out[o + nt0 * 16 + l15] = acc0[r] + bias0;
      out[o + nt1 * 16 + l15] = acc1[r] + bias1;
    }
    // next iteration's X16 write is hazard-free vs this chunk's X16 reads
    // (they completed before the barrier above); XA reads complete at the
    // next chunk's first barrier before XA is rewritten.
  }
}

// ---------------------------------------------------------------------------
extern "C" void kernel_launch(void* const* d_in, const int* in_sizes, int n_in,
                              void* d_out, int out_size, void* d_ws, size_t ws_size,
                              hipStream_t stream) {
  (void)in_sizes; (void)n_in; (void)out_size; (void)ws_size;
  const float* y0   = (const float*)d_in[0];
  const float* U    = (const float*)d_in[1];
  const float* lrc  = (const float*)d_in[2];
  const float* lic  = (const float*)d_in[3];
  const float* Bm   = (const float*)d_in[4];
  const float* Wy2x = (const float*)d_in[5];
  const float* by2x = (const float*)d_in[6];
  const float* Wx2y = (const float*)d_in[7];
  const float* bx2y = (const float*)d_in[8];
  float* out = (float*)d_out;
  float* ws  = (float*)d_ws;

  k_prep<<<dim3(NBAT + 3), 256, 0, stream>>>(y0, lrc, lic, Bm, Wy2x, by2x, Wx2y, ws);
  k_main<<<dim3(NGRP * NBAT), 128, 0, stream>>>(U, bx2y, out, ws);
}

// Round 10
// 151.957 us; speedup vs baseline: 1.3132x; 1.1532x over previous
//
#include <hip/hip_runtime.h>
#include <hip/hip_bf16.h>
#include <stdint.h>

// Problem dims
#define T_HRZ 1024
#define NBAT  128
#define NHID  256
#define NPAIR 128
#define NUIN  64
#define NYOUT 64
#define LCH   16   // chunk length
#define CCH   64   // number of chunks
#define GCH   4    // chunks per group (per block)
#define NGRP  16   // groups per batch chain = CCH/GCH

// Workspace layout (float offsets). ~2.3 MB total.
#define WS_LAM   0         // lr[128], li[128]
#define WS_LAML  256       // lambda^16 r[128], i[128]
#define WS_X0P   512       // x0 pair-interleaved [b][j][2] : 128*128*2
#define WS_WBU   33280     // bf16 B-frags for Bu GEMM [nt16][kk2][lane64][j8]
#define WS_WBY   41472     // bf16 B-frags for Y GEMM  [nt4][kk8][lane64][j8]
#define WS_S     49664     // float2 group sums [g][b][j], g in 0..14

// X16 LDS tile: packed bf16 pairs, pitch 264 shorts (132 dwords, 132%32=4)
#define X16_PITCH 264
// XA LDS tile: padded A-frag layout, b-stride 136 shorts, kk-stride 552
#define XA_SB 136
#define XA_SK 552

typedef __attribute__((ext_vector_type(8))) short short8;
typedef __attribute__((ext_vector_type(4))) float float4v;

union Frag { short8 s8; unsigned int u32[4]; };

__device__ __forceinline__ unsigned int f2bf_bits(float x) {
  unsigned int u = __float_as_uint(x);
  return (u + 0x7fffu + ((u >> 16) & 1u)) >> 16;  // RNE
}

__device__ __forceinline__ unsigned int pkbf(float a, float b) {
  __hip_bfloat162 h = __float22bfloat162_rn(make_float2(a, b));
  union { __hip_bfloat162 h2; unsigned int u; } cv; cv.h2 = h; return cv.u;
}

// ---------------------------------------------------------------------------
// K1: prep. grid (NBAT+3) x 256.
// ---------------------------------------------------------------------------
__global__ __launch_bounds__(256) void k_prep(
    const float* __restrict__ y0, const float* __restrict__ lrc,
    const float* __restrict__ lic, const float* __restrict__ Bm,
    const float* __restrict__ Wy2x, const float* __restrict__ by2x,
    const float* __restrict__ Wx2y, float* __restrict__ ws)
{
  int blk = blockIdx.x;
  int h = threadIdx.x;  // 0..255
  if (blk < NBAT) {
    __shared__ float y0s[NYOUT];
    if (h < NYOUT) y0s[h] = y0[blk * NYOUT + h];
    __syncthreads();
    float acc = by2x[h];
    const float* wr = Wy2x + h * NYOUT;
#pragma unroll 16
    for (int k = 0; k < NYOUT; ++k) acc += y0s[k] * wr[k];
    int j = h & (NPAIR - 1);
    int comp = h >> 7;
    ws[WS_X0P + (blk * NPAIR + j) * 2 + comp] = acc;
  } else if (blk == NBAT) {
    if (h < NPAIR) {
      float a  = fabsf(lrc[h]);
      float r  = expf(-a);
      float th = 1.5707963267948966f * lic[h];
      float lr = r * cosf(th);
      float li = r * sinf(th);
      ws[WS_LAM + h]         = lr;
      ws[WS_LAM + NPAIR + h] = li;
      float pr = lr, pi_ = li;
      for (int l = 1; l < LCH; ++l) {
        float nr = pr * lr - pi_ * li;
        float ni = pr * li + pi_ * lr;
        pr = nr; pi_ = ni;
      }
      ws[WS_LAML + h]         = pr;  // lambda^16
      ws[WS_LAML + NPAIR + h] = pi_;
    }
  } else if (blk == NBAT + 1) {
    unsigned short* wbu = (unsigned short*)(ws + WS_WBU);
    for (int idx = h; idx < 16384; idx += 256) {
      int nt   = idx >> 10;
      int kk   = (idx >> 9) & 1;
      int lane = (idx >> 3) & 63;
      int jj   = idx & 7;
      int u  = kk * 32 + (lane >> 4) * 8 + jj;
      int hh = nt * 16 + (lane & 15);
      float a2 = fabsf(lrc[hh & (NPAIR - 1)]);
      float nf = sqrtf(1.f - expf(-2.f * a2));
      wbu[idx] = (unsigned short)f2bf_bits(Bm[hh * NUIN + u] * nf);
    }
  } else {
    unsigned short* wby = (unsigned short*)(ws + WS_WBY);
    for (int idx = h; idx < 16384; idx += 256) {
      int nt   = idx >> 12;
      int kk   = (idx >> 9) & 7;
      int lane = (idx >> 3) & 63;
      int jj   = idx & 7;
      int hh = kk * 32 + (lane >> 4) * 8 + jj;
      int y  = nt * 16 + (lane & 15);
      wby[idx] = (unsigned short)f2bf_bits(Wx2y[y * NHID + hh]);
    }
  }
}

// ---------------------------------------------------------------------------
// K2: pass 1. grid (NBAT, NGRP-1) x 128 (2 waves). Block (b,g) computes the
// weighted group sum S[g][b][j] over its 64 steps (4 chunks of 16) and
// stores it with a PLAIN float2 store. No tickets, no atomics, no flags:
// rounds 1-9 showed intra-kernel cross-block sync costs 60-200us on this
// chip regardless of protocol (fence storm / serial chain / join+poll all
// latency-dominated). The kernel boundary is the cheapest grid barrier
// (~3-5us) and gives cache coherence for free. g=NGRP-1 is not launched
// (its S is consumed by nobody).
// ---------------------------------------------------------------------------
__global__ __launch_bounds__(128, 4) void k_pass1(
    const float* __restrict__ U, float* __restrict__ ws)
{
  __shared__ unsigned short X16s[LCH * X16_PITCH];  // 8448 B
  int tid = threadIdx.x, wave = tid >> 6, lane = tid & 63;
  int l15 = lane & 15, q = lane >> 4;
  int b = blockIdx.x, g = blockIdx.y;  // g in 0..NGRP-2

  int j = tid;
  float lr = ws[WS_LAM + j], li = ws[WS_LAM + NPAIR + j];

  const short8* wbu = (const short8*)(ws + WS_WBU);
  float4v z = {0.f, 0.f, 0.f, 0.f};
  float S1 = 0.f, S2 = 0.f;

#pragma unroll
  for (int k = 0; k < GCH; ++k) {
    int c = g * GCH + k;
    const float* urow = U + ((size_t)(c * LCH + l15) * NBAT + b) * NUIN;
    Frag afr[2];
#pragma unroll
    for (int kk = 0; kk < 2; ++kk) {
      int u0 = kk * 32 + q * 8;
      float4 va = *(const float4*)(urow + u0);
      float4 vb = *(const float4*)(urow + u0 + 4);
      afr[kk].u32[0] = pkbf(va.x, va.y);
      afr[kk].u32[1] = pkbf(va.z, va.w);
      afr[kk].u32[2] = pkbf(vb.x, vb.y);
      afr[kk].u32[3] = pkbf(vb.z, vb.w);
    }
    float4v acc[8];
#pragma unroll
    for (int n = 0; n < 8; ++n) acc[n] = z;
#pragma unroll
    for (int n = 0; n < 8; ++n) {
      int nt = wave * 8 + n;
      acc[n] = __builtin_amdgcn_mfma_f32_16x16x32_bf16(afr[0].s8, wbu[(nt * 2 + 0) * 64 + lane], acc[n], 0, 0, 0);
      acc[n] = __builtin_amdgcn_mfma_f32_16x16x32_bf16(afr[1].s8, wbu[(nt * 2 + 1) * 64 + lane], acc[n], 0, 0, 0);
    }
    // C-layout (t=q*4+r, h=(wave*8+n)*16+l15) -> packed pair LDS
#pragma unroll
    for (int n = 0; n < 8; ++n) {
      int hh = (wave * 8 + n) * 16 + l15;
      int off = (hh & 127) * 2 + (hh >> 7);
#pragma unroll
      for (int r = 0; r < 4; ++r)
        X16s[(q * 4 + r) * X16_PITCH + off] = (unsigned short)f2bf_bits(acc[n][r]);
    }
    __syncthreads();
#pragma unroll
    for (int l = 0; l < LCH; ++l) {
      unsigned int pkv = *(const unsigned int*)(X16s + l * X16_PITCH + j * 2);
      float v1 = __uint_as_float(pkv << 16);
      float v2 = __uint_as_float(pkv & 0xffff0000u);
      float n1 = lr * S1 - li * S2 + v1;
      float n2 = li * S1 + lr * S2 + v2;
      S1 = n1; S2 = n2;
    }
    if (k < GCH - 1) __syncthreads();  // X16 reads done before next overwrite
  }

  ((float2*)(ws + WS_S))[((size_t)g * NBAT + b) * NPAIR + j] = make_float2(S1, S2);
}

// ---------------------------------------------------------------------------
// K3: pass 2. grid (NBAT, NGRP) x 128 (2 waves). Block (b,g): plain-load
// the g predecessor sums S[0..g-1][b][j] (coherent across the kernel
// boundary; S is 2 MB -> L2/L3 resident), Horner e = L64*e + S, then
// recompute Bu per chunk (U re-read served by L3), finish-scan -> XA ->
// Y-MFMA -> out. No inter-block communication whatsoever.
// ---------------------------------------------------------------------------
__global__ __launch_bounds__(128, 4) void k_pass2(
    const float* __restrict__ U, const float* __restrict__ bx2y,
    float* __restrict__ out, float* __restrict__ ws)
{
  __shared__ unsigned short X16s[LCH * X16_PITCH];  // 8448 B
  __shared__ unsigned short XAs[8 * XA_SK];         // 8832 B
  int tid = threadIdx.x, wave = tid >> 6, lane = tid & 63;
  int l15 = lane & 15, q = lane >> 4;
  int b = blockIdx.x, g = blockIdx.y;  // g in 0..NGRP-1

  int j = tid;
  float lr = ws[WS_LAM + j], li = ws[WS_LAM + NPAIR + j];
  float L16r = ws[WS_LAML + j], L16i = ws[WS_LAML + NPAIR + j];
  float L32r = L16r * L16r - L16i * L16i, L32i = 2.f * L16r * L16i;
  float L64r = L32r * L32r - L32i * L32i, L64i = 2.f * L32r * L32i;

  // ---- join via plain loads: e = Horner over predecessors' S ----
  float e1 = ws[WS_X0P + (b * NPAIR + j) * 2 + 0];
  float e2 = ws[WS_X0P + (b * NPAIR + j) * 2 + 1];
  {
    const float2* sp = (const float2*)(ws + WS_S);
#pragma unroll
    for (int g2 = 0; g2 < NGRP - 1; ++g2)
      if (g2 < g) {
        float2 s = sp[((size_t)g2 * NBAT + b) * NPAIR + j];
        float n1 = L64r * e1 - L64i * e2 + s.x;
        float n2 = L64i * e1 + L64r * e2 + s.y;
        e1 = n1; e2 = n2;
      }
  }

  const short8* wbu = (const short8*)(ws + WS_WBU);
  const short8* wby = (const short8*)(ws + WS_WBY);
  float4v z = {0.f, 0.f, 0.f, 0.f};
  int base1 = (j >> 5) * XA_SK       + ((j >> 3) & 3) * XA_SB + (j & 7);
  int base2 = ((j >> 5) + 4) * XA_SK + ((j >> 3) & 3) * XA_SB + (j & 7);
  float x1 = e1, x2 = e2;
  float bias0 = bx2y[(wave * 2 + 0) * 16 + l15];
  float bias1 = bx2y[(wave * 2 + 1) * 16 + l15];

#pragma unroll
  for (int k = 0; k < GCH; ++k) {
    int c = g * GCH + k;
    // -- Bu recompute (bit-identical to pass 1) --
    const float* urow = U + ((size_t)(c * LCH + l15) * NBAT + b) * NUIN;
    Frag afr[2];
#pragma unroll
    for (int kk = 0; kk < 2; ++kk) {
      int u0 = kk * 32 + q * 8;
      float4 va = *(const float4*)(urow + u0);
      float4 vb = *(const float4*)(urow + u0 + 4);
      afr[kk].u32[0] = pkbf(va.x, va.y);
      afr[kk].u32[1] = pkbf(va.z, va.w);
      afr[kk].u32[2] = pkbf(vb.x, vb.y);
      afr[kk].u32[3] = pkbf(vb.z, vb.w);
    }
    float4v acc[8];
#pragma unroll
    for (int n = 0; n < 8; ++n) acc[n] = z;
#pragma unroll
    for (int n = 0; n < 8; ++n) {
      int nt = wave * 8 + n;
      acc[n] = __builtin_amdgcn_mfma_f32_16x16x32_bf16(afr[0].s8, wbu[(nt * 2 + 0) * 64 + lane], acc[n], 0, 0, 0);
      acc[n] = __builtin_amdgcn_mfma_f32_16x16x32_bf16(afr[1].s8, wbu[(nt * 2 + 1) * 64 + lane], acc[n], 0, 0, 0);
    }
#pragma unroll
    for (int n = 0; n < 8; ++n) {
      int hh = (wave * 8 + n) * 16 + l15;
      int off = (hh & 127) * 2 + (hh >> 7);
#pragma unroll
      for (int r = 0; r < 4; ++r)
        X16s[(q * 4 + r) * X16_PITCH + off] = (unsigned short)f2bf_bits(acc[n][r]);
    }
    __syncthreads();
    // -- scan from running x; stream X16 -> XA (separate arrays) --
#pragma unroll
    for (int l = 0; l < LCH; ++l) {
      unsigned int pkv = *(const unsigned int*)(X16s + l * X16_PITCH + j * 2);
      float v1 = __uint_as_float(pkv << 16);
      float v2 = __uint_as_float(pkv & 0xffff0000u);
      float n1 = lr * x1 - li * x2 + v1;
      float n2 = li * x1 + lr * x2 + v2;
      x1 = n1; x2 = n2;
      XAs[base1 + l * 8] = (unsigned short)f2bf_bits(x1);
      XAs[base2 + l * 8] = (unsigned short)f2bf_bits(x2);
    }
    __syncthreads();
    // -- Y = X @ W_x2y^T via MFMA --
    float4v acc0 = z, acc1 = z;
    int nt0 = wave * 2, nt1 = nt0 + 1;
#pragma unroll
    for (int kk = 0; kk < 8; ++kk) {
      short8 a = *(const short8*)(XAs + kk * XA_SK + q * XA_SB + l15 * 8);
      acc0 = __builtin_amdgcn_mfma_f32_16x16x32_bf16(a, wby[(nt0 * 8 + kk) * 64 + lane], acc0, 0, 0, 0);
      acc1 = __builtin_amdgcn_mfma_f32_16x16x32_bf16(a, wby[(nt1 * 8 + kk) * 64 + lane], acc1, 0, 0, 0);
    }
#pragma unroll
    for (int r = 0; r < 4; ++r) {
      int row = q * 4 + r;  // t within chunk
      size_t o = ((size_t)(c * LCH + row) * NBAT + b) * NYOUT;
      out[o + nt0 * 16 + l15] = acc0[r] + bias0;
      out[o + nt1 * 16 + l15] = acc1[r] + bias1;
    }
    // XA reads complete at the next chunk's first barrier before rewrite;
    // X16 writes of the next chunk are fenced by that same barrier.
  }
}

// ---------------------------------------------------------------------------
extern "C" void kernel_launch(void* const* d_in, const int* in_sizes, int n_in,
                              void* d_out, int out_size, void* d_ws, size_t ws_size,
                              hipStream_t stream) {
  (void)in_sizes; (void)n_in; (void)out_size; (void)ws_size;
  const float* y0   = (const float*)d_in[0];
  const float* U    = (const float*)d_in[1];
  const float* lrc  = (const float*)d_in[2];
  const float* lic  = (const float*)d_in[3];
  const float* Bm   = (const float*)d_in[4];
  const float* Wy2x = (const float*)d_in[5];
  const float* by2x = (const float*)d_in[6];
  const float* Wx2y = (const float*)d_in[7];
  const float* bx2y = (const float*)d_in[8];
  float* out = (float*)d_out;
  float* ws  = (float*)d_ws;

  k_prep<<<dim3(NBAT + 3), 256, 0, stream>>>(y0, lrc, lic, Bm, Wy2x, by2x, Wx2y, ws);
  k_pass1<<<dim3(NBAT, NGRP - 1), 128, 0, stream>>>(U, ws);
  k_pass2<<<dim3(NBAT, NGRP), 128, 0, stream>>>(U, bx2y, out, ws);
}

// Round 14
// 148.101 us; speedup vs baseline: 1.3474x; 1.0260x over previous
//
#include <hip/hip_runtime.h>
#include <hip/hip_bf16.h>
#include <stdint.h>

// Problem dims
#define T_HRZ 1024
#define NBAT  128
#define NHID  256
#define NPAIR 128
#define NUIN  64
#define NYOUT 64
#define LCH   16   // chunk length
#define CCH   64   // number of chunks
#define GCH   4    // chunks per group (pass-2 block)
#define NGRP  16   // groups per batch chain = CCH/GCH

// Workspace layout (float offsets). ~76 MB total (ws is 268 MB).
#define WS_LAM   0         // lr[128], li[128]
#define WS_LAML  256       // lambda^16 r[128], i[128]
#define WS_X0P   512       // x0 pair-interleaved [b][j][2] : 128*128*2
#define WS_WBU   33280     // bf16 B-frags for Bu GEMM [nt16][kk2][lane64][j8]
#define WS_WBY   41472     // bf16 B-frags for Y GEMM  [nt4][kk8][lane64][j8]
#define WS_S     49664     // float2 per-chunk sums [c][b][j] : 2,097,152 floats
#define WS_BUPK  2146816   // u32 packed Bu pairs [t][b][j] : 16,777,216 u32 (67 MB)

// X16 LDS tile: packed bf16 pairs, pitch 264 shorts (132 dwords, 132%32=4)
#define X16_PITCH 264
// XA LDS tile: padded A-frag layout, b-stride 136 shorts, kk-stride 552
#define XA_SB 136
#define XA_SK 552

typedef __attribute__((ext_vector_type(8))) short short8;
typedef __attribute__((ext_vector_type(4))) float float4v;

union Frag { short8 s8; unsigned int u32[4]; };

__device__ __forceinline__ unsigned int f2bf_bits(float x) {
  unsigned int u = __float_as_uint(x);
  return (u + 0x7fffu + ((u >> 16) & 1u)) >> 16;  // RNE
}

__device__ __forceinline__ unsigned int pkbf(float a, float b) {
  __hip_bfloat162 h = __float22bfloat162_rn(make_float2(a, b));
  union { __hip_bfloat162 h2; unsigned int u; } cv; cv.h2 = h; return cv.u;
}

// ---------------------------------------------------------------------------
// K1: prep. grid (NBAT+3) x 256.
// ---------------------------------------------------------------------------
__global__ __launch_bounds__(256) void k_prep(
    const float* __restrict__ y0, const float* __restrict__ lrc,
    const float* __restrict__ lic, const float* __restrict__ Bm,
    const float* __restrict__ Wy2x, const float* __restrict__ by2x,
    const float* __restrict__ Wx2y, float* __restrict__ ws)
{
  int blk = blockIdx.x;
  int h = threadIdx.x;  // 0..255
  if (blk < NBAT) {
    __shared__ float y0s[NYOUT];
    if (h < NYOUT) y0s[h] = y0[blk * NYOUT + h];
    __syncthreads();
    float acc = by2x[h];
    const float* wr = Wy2x + h * NYOUT;
#pragma unroll 16
    for (int k = 0; k < NYOUT; ++k) acc += y0s[k] * wr[k];
    int j = h & (NPAIR - 1);
    int comp = h >> 7;
    ws[WS_X0P + (blk * NPAIR + j) * 2 + comp] = acc;
  } else if (blk == NBAT) {
    if (h < NPAIR) {
      float a  = fabsf(lrc[h]);
      float r  = expf(-a);
      float th = 1.5707963267948966f * lic[h];
      float lr = r * cosf(th);
      float li = r * sinf(th);
      ws[WS_LAM + h]         = lr;
      ws[WS_LAM + NPAIR + h] = li;
      float pr = lr, pi_ = li;
      for (int l = 1; l < LCH; ++l) {
        float nr = pr * lr - pi_ * li;
        float ni = pr * li + pi_ * lr;
        pr = nr; pi_ = ni;
      }
      ws[WS_LAML + h]         = pr;  // lambda^16
      ws[WS_LAML + NPAIR + h] = pi_;
    }
  } else if (blk == NBAT + 1) {
    unsigned short* wbu = (unsigned short*)(ws + WS_WBU);
    for (int idx = h; idx < 16384; idx += 256) {
      int nt   = idx >> 10;
      int kk   = (idx >> 9) & 1;
      int lane = (idx >> 3) & 63;
      int jj   = idx & 7;
      int u  = kk * 32 + (lane >> 4) * 8 + jj;
      int hh = nt * 16 + (lane & 15);
      float a2 = fabsf(lrc[hh & (NPAIR - 1)]);
      float nf = sqrtf(1.f - expf(-2.f * a2));
      wbu[idx] = (unsigned short)f2bf_bits(Bm[hh * NUIN + u] * nf);
    }
  } else {
    unsigned short* wby = (unsigned short*)(ws + WS_WBY);
    for (int idx = h; idx < 16384; idx += 256) {
      int nt   = idx >> 12;
      int kk   = (idx >> 9) & 7;
      int lane = (idx >> 3) & 63;
      int jj   = idx & 7;
      int hh = kk * 32 + (lane >> 4) * 8 + jj;
      int y  = nt * 16 + (lane & 15);
      wby[idx] = (unsigned short)f2bf_bits(Wx2y[y * NHID + hh]);
    }
  }
}

// ---------------------------------------------------------------------------
// K2: pass 1 — per-CHUNK Bu producer. grid (NBAT, CCH) x 128 (2 waves).
// Block (b,c): U chunk -> Bu MFMA -> X16 transpose -> per-thread packed
// column; stores (a) the packed bf16 Bu u32 to global Bu_pk[t][b][j]
// (coalesced 512B rows) and (b) the chunk's weighted sum s[c][b][j].
// One chunk per block = maximum parallelism, shortest serial chain.
// Pass 2 then never touches U or the Bu MFMA again (round-9/10 showed the
// recompute front-end is the latency bottleneck, not bandwidth).
// ---------------------------------------------------------------------------
__global__ __launch_bounds__(128, 4) void k_pass1(
    const float* __restrict__ U, float* __restrict__ ws)
{
  __shared__ unsigned short X16s[LCH * X16_PITCH];  // 8448 B
  int tid = threadIdx.x, wave = tid >> 6, lane = tid & 63;
  int l15 = lane & 15, q = lane >> 4;
  int b = blockIdx.x, c = blockIdx.y;

  int j = tid;
  float lr = ws[WS_LAM + j], li = ws[WS_LAM + NPAIR + j];

  const short8* wbu = (const short8*)(ws + WS_WBU);
  float4v z = {0.f, 0.f, 0.f, 0.f};

  const float* urow = U + ((size_t)(c * LCH + l15) * NBAT + b) * NUIN;
  Frag afr[2];
#pragma unroll
  for (int kk = 0; kk < 2; ++kk) {
    int u0 = kk * 32 + q * 8;
    float4 va = *(const float4*)(urow + u0);
    float4 vb = *(const float4*)(urow + u0 + 4);
    afr[kk].u32[0] = pkbf(va.x, va.y);
    afr[kk].u32[1] = pkbf(va.z, va.w);
    afr[kk].u32[2] = pkbf(vb.x, vb.y);
    afr[kk].u32[3] = pkbf(vb.z, vb.w);
  }
  float4v acc[8];
#pragma unroll
  for (int n = 0; n < 8; ++n) acc[n] = z;
#pragma unroll
  for (int n = 0; n < 8; ++n) {
    int nt = wave * 8 + n;
    acc[n] = __builtin_amdgcn_mfma_f32_16x16x32_bf16(afr[0].s8, wbu[(nt * 2 + 0) * 64 + lane], acc[n], 0, 0, 0);
    acc[n] = __builtin_amdgcn_mfma_f32_16x16x32_bf16(afr[1].s8, wbu[(nt * 2 + 1) * 64 + lane], acc[n], 0, 0, 0);
  }
  // C-layout (t=q*4+r, h=(wave*8+n)*16+l15) -> packed pair LDS
#pragma unroll
  for (int n = 0; n < 8; ++n) {
    int hh = (wave * 8 + n) * 16 + l15;
    int off = (hh & 127) * 2 + (hh >> 7);
#pragma unroll
    for (int r = 0; r < 4; ++r)
      X16s[(q * 4 + r) * X16_PITCH + off] = (unsigned short)f2bf_bits(acc[n][r]);
  }
  __syncthreads();

  unsigned int* bupk = (unsigned int*)(ws + WS_BUPK);
  float S1 = 0.f, S2 = 0.f;
#pragma unroll
  for (int l = 0; l < LCH; ++l) {
    unsigned int pkv = *(const unsigned int*)(X16s + l * X16_PITCH + j * 2);
    bupk[((size_t)(c * LCH + l) * NBAT + b) * NPAIR + j] = pkv;
    float v1 = __uint_as_float(pkv << 16);
    float v2 = __uint_as_float(pkv & 0xffff0000u);
    float n1 = lr * S1 - li * S2 + v1;
    float n2 = li * S1 + lr * S2 + v2;
    S1 = n1; S2 = n2;
  }
  ((float2*)(ws + WS_S))[((size_t)c * NBAT + b) * NPAIR + j] = make_float2(S1, S2);
}

// ---------------------------------------------------------------------------
// K3: pass 2 — streaming consumer. grid (NBAT, NGRP) x 128 (2 waves).
// Block (b,g): (1) Horner-join e = Lam16-prefix over the 4g predecessor
// chunk sums (8.4 MB s[] is L2-resident; loads batched 8-wide to hide
// latency), (2) per chunk: plain-load the packed Bu u32 column, 16-step
// scan -> XA LDS -> Y-MFMA -> out. No U read, no Bu MFMA, no X16, only
// the XA barrier pair per chunk. Coherence across the kernel boundary is
// free; no inter-block communication anywhere.
// ---------------------------------------------------------------------------
__global__ __launch_bounds__(128, 4) void k_pass2(
    const float* __restrict__ bx2y, float* __restrict__ out,
    float* __restrict__ ws)
{
  __shared__ unsigned short XAs[8 * XA_SK];  // 8832 B
  int tid = threadIdx.x, wave = tid >> 6, lane = tid & 63;
  int l15 = lane & 15, q = lane >> 4;
  int b = blockIdx.x, g = blockIdx.y;  // g in 0..NGRP-1

  int j = tid;
  float lr = ws[WS_LAM + j],  li = ws[WS_LAM + NPAIR + j];
  float L16r = ws[WS_LAML + j], L16i = ws[WS_LAML + NPAIR + j];

  // ---- join: Lam16 Horner over predecessor chunk sums (batched loads) ----
  float e1 = ws[WS_X0P + (b * NPAIR + j) * 2 + 0];
  float e2 = ws[WS_X0P + (b * NPAIR + j) * 2 + 1];
  {
    const float2* sp = (const float2*)(ws + WS_S);
    size_t o0 = (size_t)b * NPAIR + j;
    int nc = g * GCH;  // 0..60, multiple of 4
    for (int c2 = 0; c2 < nc; c2 += 8) {
      float2 v[8];
#pragma unroll
      for (int t = 0; t < 8; ++t)
        if (c2 + t < nc) v[t] = sp[(size_t)(c2 + t) * (NBAT * NPAIR) + o0];
#pragma unroll
      for (int t = 0; t < 8; ++t)
        if (c2 + t < nc) {
          float n1 = L16r * e1 - L16i * e2 + v[t].x;
          float n2 = L16i * e1 + L16r * e2 + v[t].y;
          e1 = n1; e2 = n2;
        }
    }
  }

  const unsigned int* bupk = (const unsigned int*)(ws + WS_BUPK);
  const short8* wby = (const short8*)(ws + WS_WBY);
  float4v z = {0.f, 0.f, 0.f, 0.f};
  int base1 = (j >> 5) * XA_SK       + ((j >> 3) & 3) * XA_SB + (j & 7);
  int base2 = ((j >> 5) + 4) * XA_SK + ((j >> 3) & 3) * XA_SB + (j & 7);
  float x1 = e1, x2 = e2;
  float bias0 = bx2y[(wave * 2 + 0) * 16 + l15];
  float bias1 = bx2y[(wave * 2 + 1) * 16 + l15];

#pragma unroll
  for (int k = 0; k < GCH; ++k) {
    int c = g * GCH + k;
    // -- load packed Bu column (streaming, independent loads) --
    unsigned int pk[LCH];
#pragma unroll
    for (int l = 0; l < LCH; ++l)
      pk[l] = bupk[((size_t)(c * LCH + l) * NBAT + b) * NPAIR + j];
    // -- scan from running x; write bf16 X into XA --
#pragma unroll
    for (int l = 0; l < LCH; ++l) {
      float v1 = __uint_as_float(pk[l] << 16);
      float v2 = __uint_as_float(pk[l] & 0xffff0000u);
      float n1 = lr * x1 - li * x2 + v1;
      float n2 = li * x1 + lr * x2 + v2;
      x1 = n1; x2 = n2;
      XAs[base1 + l * 8] = (unsigned short)f2bf_bits(x1);
      XAs[base2 + l * 8] = (unsigned short)f2bf_bits(x2);
    }
    __syncthreads();
    // -- Y = X @ W_x2y^T via MFMA --
    float4v acc0 = z, acc1 = z;
    int nt0 = wave * 2, nt1 = nt0 + 1;
#pragma unroll
    for (int kk = 0; kk < 8; ++kk) {
      short8 a = *(const short8*)(XAs + kk * XA_SK + q * XA_SB + l15 * 8);
      acc0 = __builtin_amdgcn_mfma_f32_16x16x32_bf16(a, wby[(nt0 * 8 + kk) * 64 + lane], acc0, 0, 0, 0);
      acc1 = __builtin_amdgcn_mfma_f32_16x16x32_bf16(a, wby[(nt1 * 8 + kk) * 64 + lane], acc1, 0, 0, 0);
    }
#pragma unroll
    for (int r = 0; r < 4; ++r) {
      int row = q * 4 + r;  // t within chunk
      size_t o = ((size_t)(c * LCH + row) * NBAT + b) * NYOUT;
      out[o + nt0 * 16 + l15] = acc0[r] + bias0;
      out[o + nt1 * 16 + l15] = acc1[r] + bias1;
    }
    if (k < GCH - 1) __syncthreads();  // XA reads done before next overwrite
  }
}

// ---------------------------------------------------------------------------
extern "C" void kernel_launch(void* const* d_in, const int* in_sizes, int n_in,
                              void* d_out, int out_size, void* d_ws, size_t ws_size,
                              hipStream_t stream) {
  (void)in_sizes; (void)n_in; (void)out_size; (void)ws_size;
  const float* y0   = (const float*)d_in[0];
  const float* U    = (const float*)d_in[1];
  const float* lrc  = (const float*)d_in[2];
  const float* lic  = (const float*)d_in[3];
  const float* Bm   = (const float*)d_in[4];
  const float* Wy2x = (const float*)d_in[5];
  const float* by2x = (const float*)d_in[6];
  const float* Wx2y = (const float*)d_in[7];
  const float* bx2y = (const float*)d_in[8];
  float* out = (float*)d_out;
  float* ws  = (float*)d_ws;

  k_prep<<<dim3(NBAT + 3), 256, 0, stream>>>(y0, lrc, lic, Bm, Wy2x, by2x, Wx2y, ws);
  k_pass1<<<dim3(NBAT, CCH), 128, 0, stream>>>(U, ws);
  k_pass2<<<dim3(NBAT, NGRP), 128, 0, stream>>>(bx2y, out, ws);
}